// Round 6
// baseline (2982.461 us; speedup 1.0000x reference)
//
#include <hip/hip_runtime.h>
#include <hip/hip_bf16.h>

#define B_SZ 4096
#define T_SZ 64
#define F_SZ 89
#define H_SZ 1024
#define O_SZ 89
#define KX   128
#define KTOT (KX + H_SZ)   // 1152
#define NSL_FULL (KTOT / 32)   // 36 K-slices of 32

typedef __attribute__((ext_vector_type(8))) short bf16x8;
typedef __attribute__((ext_vector_type(4))) float f32x4;

__device__ __forceinline__ void gload_lds16(const void* g, void* l) {
  __builtin_amdgcn_global_load_lds((const __attribute__((address_space(1))) void*)g,
                                   (__attribute__((address_space(3))) void*)l,
                                   16, 0, 0);
}
__device__ __forceinline__ float sigmoidf_(float x) {
  return 1.0f / (1.0f + __expf(-x));
}

// WT2 packed: n' = (h>>4)*64 + g*16 + (h&15), bf16, [4096][1152] k-contiguous rows.
__global__ __launch_bounds__(256) void pack_w(const float* __restrict__ Wk,
                                              const float* __restrict__ Wr,
                                              __hip_bfloat16* __restrict__ WT2) {
  __shared__ float tile[64][65];
  const int n0 = blockIdx.x * 64;
  const int k0 = blockIdx.y * 64;
  const int c  = threadIdx.x & 63;
  const int rq = threadIdx.x >> 6;
  for (int j = 0; j < 16; ++j) {
    int kk = rq * 16 + j;
    int k = k0 + kk;
    float v;
    if (k < KX) v = (k < F_SZ) ? Wk[(size_t)k * 4096 + n0 + c] : 0.0f;
    else        v = Wr[(size_t)(k - KX) * 4096 + n0 + c];
    tile[kk][c] = v;
  }
  __syncthreads();
  for (int j = 0; j < 16; ++j) {
    int R = n0 + rq * 16 + j;          // orig row: g*1024 + h
    int g = R >> 10, h = R & 1023;
    int np = ((h >> 4) << 6) + (g << 4) + (h & 15);
    WT2[(size_t)np * KTOT + k0 + c] = __float2bfloat16(tile[c][rq * 16 + j]);
  }
}

// xp [T][B][128] bf16, zero-padded cols 89..127. Wave-per-row, coalesced; unroll 4 for ILP.
__global__ __launch_bounds__(256) void pack_x(const float* __restrict__ x,
                                              __hip_bfloat16* __restrict__ xp) {
  const int wid = (blockIdx.x * 256 + threadIdx.x) >> 6;  // 0..8191
  const int l   = threadIdx.x & 63;
#pragma unroll 4
  for (int r = wid; r < T_SZ * B_SZ; r += 8192) {
    const int t = r >> 12, m = r & 4095;
    const float* src = x + ((size_t)m * T_SZ + t) * F_SZ;
    float v0 = src[l];
    float v1 = (64 + l < F_SZ) ? src[64 + l] : 0.0f;
    __hip_bfloat16* dst = xp + (size_t)r * KX;
    dst[l]      = __float2bfloat16(v0);
    dst[64 + l] = __float2bfloat16(v1);
  }
}

// WdT2[2][96][1024] bf16: pass0 = bf16(Wd^T), pass1 = bf16(Wd^T - pass0)
__global__ __launch_bounds__(256) void pack_wd(const float* __restrict__ Wd,
                                               __hip_bfloat16* __restrict__ WdT2) {
  int o = blockIdx.x;  // 0..95
  for (int k = threadIdx.x; k < 1024; k += 256) {
    float v = (o < O_SZ) ? Wd[(size_t)k * O_SZ + o] : 0.0f;
    __hip_bfloat16 w1 = __float2bfloat16(v);
    WdT2[(size_t)o * 1024 + k] = w1;
    WdT2[96 * 1024 + (size_t)o * 1024 + k] = __float2bfloat16(v - __bfloat162float(w1));
  }
}

// ---------------- LSTM step: 256x256 tile, ring-of-4 K-slice-32, frag-read pipelined ----
// Ring-4 slots; stage distance 3; boundary vmcnt(4) makes slice ks+1 resident at END of
// iter ks-1 -> iter ks reads slice ks+1's frags BETWEEN its MFMA halves (LDS overlaps MFMA).
// One barrier/slice; vmcnt never drained to 0 mid-loop. Swizzle involution conflict-free
// (8 lanes per 4-bank group on reads; linear gload writes).
template <int NSL, bool FIRST>
__global__ __launch_bounds__(512, 2)
void lstm_step(const __hip_bfloat16* __restrict__ xp_t,   // [4096][128]
               const __hip_bfloat16* __restrict__ h_in,   // [4096][1024]
               __hip_bfloat16* __restrict__ h_out,
               float* __restrict__ cbuf,
               const __hip_bfloat16* __restrict__ WT2,    // [4096][1152] packed
               const float* __restrict__ bias,
               __hip_bfloat16* __restrict__ h2_out)       // null or bf16 residual of h
{
  __shared__ __attribute__((aligned(1024))) char smem[131072];

  const int tid  = threadIdx.x;
  const int lane = tid & 63;
  const int w    = tid >> 6;
  const int wm   = w >> 2;     // 0..1  (M half)
  const int wn   = w & 3;      // 0..3  (64-packed-col strip)

  const int bid = blockIdx.x;
  const int wg  = (bid & 7) * 32 + (bid >> 3);   // XCD-aware swizzle (256 wgs, 8 XCDs)
  const int bx  = wg >> 4;
  const int by  = wg & 15;
  const int m0  = bx * 256;

  const int s_rl = lane >> 2;
  const int s_cb = (((lane & 3) ^ ((lane >> 3) & 3)) << 4);
  const int lr = lane & 15, lq = lane >> 4;
  const int cc = ((lq ^ ((lr >> 1) & 3)) << 4);
  const int aoff = (wm * 128 + lr) * 64 + cc;
  const int boff = (wn * 64 + lr) * 64 + cc;

  const char* bsrc0 = (const char*)(WT2 + (size_t)by * 256 * KTOT);

  f32x4 acc[8][4];
#pragma unroll
  for (int mi = 0; mi < 8; ++mi)
#pragma unroll
    for (int ni = 0; ni < 4; ++ni) acc[mi][ni] = (f32x4){0.f, 0.f, 0.f, 0.f};

  auto stageA = [&](int s) {   // slice s -> A slot s&3 (2 gload_lds)
    const char* base; int ldb;
    if (s < 4) { base = (const char*)xp_t + ((size_t)m0 * KX) * 2 + s * 64;           ldb = KX * 2; }
    else       { base = (const char*)h_in + ((size_t)m0 * H_SZ) * 2 + (s * 64 - 256); ldb = H_SZ * 2; }
    char* slot = smem + (s & 3) * 16384;
#pragma unroll
    for (int j = 0; j < 2; ++j) {
      int row = (j * 8 + w) * 16 + s_rl;
      gload_lds16(base + (size_t)row * ldb + s_cb, slot + (j * 8 + w) * 1024);
    }
  };
  auto stageB = [&](int s) {   // slice s -> B slot s&3
    char* slot = smem + 65536 + (s & 3) * 16384;
#pragma unroll
    for (int j = 0; j < 2; ++j) {
      int row = (j * 8 + w) * 16 + s_rl;
      gload_lds16(bsrc0 + (size_t)row * (KTOT * 2) + s * 64 + s_cb, slot + (j * 8 + w) * 1024);
    }
  };

  bf16x8 AfA[8], BfA[4], AfB[8], BfB[4];

  auto frag_read0 = [&](int s, bf16x8 (&Af)[8], bf16x8 (&Bf)[4]) {
    const char* An = smem + (s & 3) * 16384;
    const char* Bn = smem + 65536 + (s & 3) * 16384;
#pragma unroll
    for (int ni = 0; ni < 4; ++ni) Bf[ni] = *(const bf16x8*)(Bn + boff + ni * 1024);
#pragma unroll
    for (int mi = 0; mi < 4; ++mi) Af[mi] = *(const bf16x8*)(An + aoff + mi * 1024);
  };
  auto frag_read1 = [&](int s, bf16x8 (&Af)[8]) {
    const char* An = smem + (s & 3) * 16384;
#pragma unroll
    for (int mi = 4; mi < 8; ++mi) Af[mi] = *(const bf16x8*)(An + aoff + mi * 1024);
  };
  auto mfma_h0 = [&](bf16x8 (&Af)[8], bf16x8 (&Bf)[4]) {
    __builtin_amdgcn_s_setprio(1);
#pragma unroll
    for (int mi = 0; mi < 4; ++mi)
#pragma unroll
      for (int ni = 0; ni < 4; ++ni)
        acc[mi][ni] = __builtin_amdgcn_mfma_f32_16x16x32_bf16(Af[mi], Bf[ni], acc[mi][ni], 0, 0, 0);
    __builtin_amdgcn_s_setprio(0);
  };
  auto mfma_h1 = [&](bf16x8 (&Af)[8], bf16x8 (&Bf)[4]) {
    __builtin_amdgcn_s_setprio(1);
#pragma unroll
    for (int mi = 4; mi < 8; ++mi)
#pragma unroll
      for (int ni = 0; ni < 4; ++ni)
        acc[mi][ni] = __builtin_amdgcn_mfma_f32_16x16x32_bf16(Af[mi], Bf[ni], acc[mi][ni], 0, 0, 0);
    __builtin_amdgcn_s_setprio(0);
  };

  auto body = [&](int ks, bf16x8 (&ACur)[8], bf16x8 (&BCur)[4],
                  bf16x8 (&ANxt)[8], bf16x8 (&BNxt)[4]) {
    if (ks + 3 < NSL) { stageA(ks + 3); stageB(ks + 3); }   // 4 gloads -> dead slot
    mfma_h0(ACur, BCur);
    if (ks + 1 < NSL) frag_read0(ks + 1, ANxt, BNxt);       // slot resident since prev boundary
    mfma_h1(ACur, BCur);
    if (ks + 1 < NSL) frag_read1(ks + 1, ANxt);
    // boundary: drain slice ks+2 (oldest 4 in flight); ks+3's 4 stay in flight
    if (ks + 3 < NSL)       asm volatile("s_waitcnt vmcnt(4)" ::: "memory");
    else if (ks + 3 == NSL) asm volatile("s_waitcnt vmcnt(0)" ::: "memory");
    if (ks + 1 < NSL) __builtin_amdgcn_s_barrier();
  };

  // prologue: stage slices 0,1,2; slice0 resident -> read frags; slice1 resident
  stageA(0); stageB(0);
  stageA(1); stageB(1);
  stageA(2); stageB(2);
  asm volatile("s_waitcnt vmcnt(8)" ::: "memory");
  __builtin_amdgcn_s_barrier();
  frag_read0(0, AfA, BfA);
  frag_read1(0, AfA);
  asm volatile("s_waitcnt vmcnt(4)" ::: "memory");
  __builtin_amdgcn_s_barrier();

#pragma unroll 1
  for (int kp = 0; kp < NSL / 2; ++kp) {
    body(2 * kp,     AfA, BfA, AfB, BfB);
    body(2 * kp + 1, AfB, BfB, AfA, BfA);
  }

  // ---- epilogue: all 4 gates wave-local (ni == gate via WT2 packing) ----
  const int hcol = by * 64 + wn * 16 + lr;
  const float b0 = bias[hcol];
  const float b2 = bias[2 * H_SZ + hcol];
  const float b3 = bias[3 * H_SZ + hcol];
  float b1 = 0.0f;
  if constexpr (!FIRST) b1 = bias[H_SZ + hcol];
#pragma unroll
  for (int mi = 0; mi < 8; ++mi) {
#pragma unroll
    for (int v = 0; v < 4; ++v) {
      int r = m0 + wm * 128 + mi * 16 + lq * 4 + v;
      size_t idx = (size_t)r * H_SZ + hcol;
      float iv = sigmoidf_(acc[mi][0][v] + b0);
      float gv = fmaxf(acc[mi][2][v] + b2, 0.0f);
      float ov = sigmoidf_(acc[mi][3][v] + b3);
      float cn;
      if constexpr (FIRST) {
        cn = iv * gv;                       // c_prev = 0, f*0 drops
      } else {
        float fv = sigmoidf_(acc[mi][1][v] + b1);
        cn = fv * cbuf[idx] + iv * gv;
      }
      cbuf[idx] = cn;
      float hv = ov * fmaxf(cn, 0.0f);
      __hip_bfloat16 h1 = __float2bfloat16(hv);
      h_out[idx] = h1;
      if (h2_out) h2_out[idx] = __float2bfloat16(hv - __bfloat162float(h1));
    }
  }
}

// ---------------- dense: out = h @ Wd + bd via 3-pass bf16 MFMA (fp32-accurate) ----------------
__global__ __launch_bounds__(256)
void dense_k(const __hip_bfloat16* __restrict__ h1,
             const __hip_bfloat16* __restrict__ h2,
             const __hip_bfloat16* __restrict__ WdT2,  // [2][96][1024]
             const float* __restrict__ bd,
             float* __restrict__ out) {
  __shared__ __attribute__((aligned(1024))) char smem[8192 + 12288]; // A[64][128B] + B[96][128B]
  const int tid = threadIdx.x, lane = tid & 63, w = tid >> 6;
  const int m0 = blockIdx.x * 64;
  const int lr = lane & 15, lq = lane >> 4;
  const int s_cb = (((lane & 7) ^ ((lane >> 3) & 7)) << 4);

  f32x4 acc[6];
#pragma unroll
  for (int ni = 0; ni < 6; ++ni) acc[ni] = (f32x4){0.f, 0.f, 0.f, 0.f};

  for (int p = 0; p < 3; ++p) {
    const __hip_bfloat16* Asrc = (p < 2) ? h1 : h2;
    const __hip_bfloat16* Bsrc = WdT2 + (p == 1 ? 96 * 1024 : 0);
    for (int kb = 0; kb < 16; ++kb) {
      __syncthreads();
#pragma unroll
      for (int j = 0; j < 2; ++j) {
        int row = j * 32 + w * 8 + (lane >> 3);
        gload_lds16((const char*)(Asrc + (size_t)(m0 + row) * 1024 + kb * 64) + s_cb,
                    smem + j * 4096 + w * 1024);
      }
#pragma unroll
      for (int j = 0; j < 3; ++j) {
        int row = j * 32 + w * 8 + (lane >> 3);
        gload_lds16((const char*)(Bsrc + (size_t)row * 1024 + kb * 64) + s_cb,
                    smem + 8192 + j * 4096 + w * 1024);
      }
      __syncthreads();

      bf16x8 Af[2], Bf[6][2];
#pragma unroll
      for (int ks = 0; ks < 2; ++ks)
        Af[ks] = *(const bf16x8*)(smem + (w * 16 + lr) * 128 + (((4 * ks + lq) ^ (lr & 7)) << 4));
#pragma unroll
      for (int ni = 0; ni < 6; ++ni)
#pragma unroll
        for (int ks = 0; ks < 2; ++ks)
          Bf[ni][ks] = *(const bf16x8*)(smem + 8192 + (ni * 16 + lr) * 128 + (((4 * ks + lq) ^ (lr & 7)) << 4));
#pragma unroll
      for (int ni = 0; ni < 6; ++ni)
#pragma unroll
        for (int ks = 0; ks < 2; ++ks)
          acc[ni] = __builtin_amdgcn_mfma_f32_16x16x32_bf16(Af[ks], Bf[ni][ks], acc[ni], 0, 0, 0);
    }
  }

#pragma unroll
  for (int ni = 0; ni < 6; ++ni) {
    int o = ni * 16 + lr;
    if (o < O_SZ) {
      float bv = bd[o];
#pragma unroll
      for (int v = 0; v < 4; ++v) {
        int r = m0 + w * 16 + lq * 4 + v;
        out[(size_t)r * O_SZ + o] = acc[ni][v] + bv;
      }
    }
  }
}

extern "C" void kernel_launch(void* const* d_in, const int* in_sizes, int n_in,
                              void* d_out, int out_size, void* d_ws, size_t ws_size,
                              hipStream_t stream) {
  const float* x  = (const float*)d_in[0];
  const float* Wk = (const float*)d_in[1];
  const float* Wr = (const float*)d_in[2];
  const float* b  = (const float*)d_in[3];
  const float* Wd = (const float*)d_in[4];
  const float* bd = (const float*)d_in[5];
  float* out = (float*)d_out;

  char* ws = (char*)d_ws;
  size_t off = 0;
  auto carve = [&](size_t bytes) -> char* {
    char* p = ws + off;
    off += (bytes + 255) & ~(size_t)255;
    return p;
  };
  __hip_bfloat16* WT2  = (__hip_bfloat16*)carve((size_t)4096 * KTOT * 2);
  __hip_bfloat16* xp   = (__hip_bfloat16*)carve((size_t)T_SZ * B_SZ * KX * 2);
  __hip_bfloat16* h0   = (__hip_bfloat16*)carve((size_t)B_SZ * H_SZ * 2);
  __hip_bfloat16* h1b  = (__hip_bfloat16*)carve((size_t)B_SZ * H_SZ * 2);
  float*          cbuf = (float*)carve((size_t)B_SZ * H_SZ * 4);
  __hip_bfloat16* h2   = (__hip_bfloat16*)carve((size_t)B_SZ * H_SZ * 2);
  __hip_bfloat16* WdT2 = (__hip_bfloat16*)carve((size_t)2 * 96 * 1024 * 2);

  pack_w<<<dim3(64, 18), 256, 0, stream>>>(Wk, Wr, WT2);
  pack_x<<<2048, 256, 0, stream>>>(x, xp);
  pack_wd<<<96, 256, 0, stream>>>(Wd, WdT2);

  __hip_bfloat16* hbuf[2] = {h0, h1b};
  // t = 0: h_in == 0 -> only the 4 x-slices of K; writes c = i*g (no cbuf read, no memsets)
  lstm_step<4, true><<<256, 512, 0, stream>>>(xp, hbuf[0], hbuf[1], cbuf, WT2, b, nullptr);
  for (int t = 1; t < T_SZ; ++t) {
    const __hip_bfloat16* xpt = xp + (size_t)t * B_SZ * KX;
    lstm_step<NSL_FULL, false><<<256, 512, 0, stream>>>(xpt, hbuf[t & 1], hbuf[(t + 1) & 1],
                                                        cbuf, WT2, b,
                                                        (t == T_SZ - 1) ? h2 : nullptr);
  }

  // final h is in hbuf[T&1] = hbuf[0]
  dense_k<<<64, 256, 0, stream>>>(hbuf[0], h2, WdT2, bd, out);
}